// Round 12
// baseline (600.287 us; speedup 1.0000x reference)
//
#include <hip/hip_runtime.h>
#include <cstdint>
#include <cstddef>

// ---------------------------------------------------------------------------
// Pointer-network decoder: B=128 batches decode T=32 steps over N=512 nodes.
// Round 14 = R11 with the two setup kernels MERGED into one launch.
// Key enabler: W1P was algebraically redundant -- W1P float4 (h4*128+k) ==
// ((float4*)W1)[k*32+h4] (W1 rows contiguous in h), so k_enc_trans reads W1
// directly with IDENTICAL float4 values -> identical FMA expressions ->
// encT2 bit-identical. With that dependency gone, transpose (Wih/Whh/W2)
// and enc_trans are both input-only: one grid, blocks 0..1023 = enc_trans,
// 1024..1599 = transpose. Saves one launch interval (~5-10us).
// k_decode: R10/R11 BYTE-FOR-BYTE (475-495us, FETCH 35MB, spill-free;
// R6-R9 proved every deeper k_decode restructure regresses >=3x; R9 proved
// packing ITS weight streams breaks L2 residency -- scalar loads preserved).
// All accumulation chains bit-identical -> absmax 0.0.
// ---------------------------------------------------------------------------

constexpr int B = 128, N = 512, H = 128, T = 32;
constexpr int G4 = 4 * H;  // 512
constexpr float TINYF = 1.17549435e-38f;  // np.finfo(float32).tiny

// ---- JAX threefry2x32 block cipher (20 rounds) ----------------------------
__host__ __device__ inline uint32_t rotl32(uint32_t v, int d) {
  return (v << d) | (v >> (32 - d));
}

__host__ __device__ inline void tf2x32(uint32_t k0, uint32_t k1,
                                       uint32_t x0, uint32_t x1,
                                       uint32_t& o0, uint32_t& o1) {
  uint32_t ks2 = k0 ^ k1 ^ 0x1BD11BDAu;
  x0 += k0; x1 += k1;
#define TF_R(r) x0 += x1; x1 = rotl32(x1, (r)); x1 ^= x0;
  TF_R(13) TF_R(15) TF_R(26) TF_R(6)
  x0 += k1; x1 += ks2 + 1u;
  TF_R(17) TF_R(29) TF_R(16) TF_R(24)
  x0 += ks2; x1 += k0 + 2u;
  TF_R(13) TF_R(15) TF_R(26) TF_R(6)
  x0 += k0; x1 += k1 + 3u;
  TF_R(17) TF_R(29) TF_R(16) TF_R(24)
  x0 += k1; x1 += ks2 + 4u;
  TF_R(13) TF_R(15) TF_R(26) TF_R(6)
  x0 += ks2; x1 += k0 + 5u;
#undef TF_R
  o0 = x0; o1 = x1;
}

struct KeyArgs { uint32_t k[2 * T]; };  // per-step subkeys, 256 B by value

// Host-side key chain (partitionable split): key0 = (0,42);
// new_key = E_key(0,0), sub = E_key(0,1).
static KeyArgs make_subkeys() {
  KeyArgs ka;
  uint32_t k0 = 0u, k1 = 42u;
  for (int t = 0; t < T; ++t) {
    uint32_t n0, n1, s0, s1;
    tf2x32(k0, k1, 0u, 0u, n0, n1);
    tf2x32(k0, k1, 0u, 1u, s0, s1);
    ka.k[2 * t] = s0; ka.k[2 * t + 1] = s1;
    k0 = n0; k1 = n1;
  }
  return ka;
}

// 32-bit draw i (of 65536) for this step's subkey: w0^w1 of E_sub(0, i)
__device__ inline uint32_t gumbel_bits(uint32_t sk0, uint32_t sk1, int i) {
  uint32_t o0, o1;
  tf2x32(sk0, sk1, 0u, (uint32_t)i, o0, o1);
  return o0 ^ o1;
}

// fast tanh for the score hot loop; abs err ~2e-7 (clamp avoids inf/inf NaN)
__device__ inline float fast_tanh(float x) {
  float cx = fminf(9.0f, fmaxf(-9.0f, x));
  float t = __expf(2.0f * cx);
  return (t - 1.0f) * __builtin_amdgcn_rcpf(t + 1.0f);
}

// ---- merged setup kernel ---------------------------------------------------
// Blocks 0..1023: encT2[b,k,n] = sum_h enc[b,n,h]*W1[k,h] (R11's retile,
//   W1 read DIRECTLY as float4 rows -- same values as the old W1P pack).
// Blocks 1024..1599: weight transposes for k_decode (R4/R10 layouts --
//   scalar-load streams; R9 proved packing them breaks L2 residency).
// No cross-block dependencies: both halves read only kernel inputs.
__global__ __launch_bounds__(256) void k_setup(
    const float* __restrict__ enc, const float* __restrict__ W1,
    const float* __restrict__ Wih, const float* __restrict__ Whh,
    const float* __restrict__ W2,
    float* __restrict__ encT2, float* __restrict__ WihT,
    float* __restrict__ WhhT, float* __restrict__ W2T) {
  __shared__ __align__(16) float es[64 * 128];  // 32 KB (enc_trans blocks only)
  const int tid = threadIdx.x;

  if (blockIdx.x >= 1024) {
    // ---- transpose half: i in [0, 2*H*G4 + H*H) = [0, 147456) ----
    int i = (blockIdx.x - 1024) * 256 + tid;
    if (i < H * G4) {
      int h = i >> 9, j = i & (G4 - 1);
      WihT[i] = Wih[j * H + h];
    } else if (i < 2 * H * G4) {
      int q = i - H * G4; int h = q >> 9, j = q & (G4 - 1);
      WhhT[q] = Whh[j * H + h];
    } else {
      int q = i - 2 * H * G4; int h = q >> 7, k = q & (H - 1);
      W2T[q] = W2[k * H + h];
    }
    return;
  }

  // ---- enc_trans half: 1024 blocks (128 b x 8 chunks of 64 n-rows) ----
  const int blk = blockIdx.x;
  const int b = blk >> 3;              // 8 blocks per batch
  const int n0 = (blk & 7) << 6;       // 64 rows per block

  // stage enc[b][n0..n0+63][:], coalesced float4
  {
    const float4* src4 = (const float4*)(enc + ((size_t)b * N + n0) * H);
    float4* dst4 = (float4*)es;
#pragma unroll
    for (int i = 0; i < 8; ++i) dst4[tid + i * 256] = src4[tid + i * 256];
  }
  __syncthreads();

  const int kq = tid & 31;             // k-quad: k = kq*4 .. kq*4+3
  const int ng = tid >> 5;             // n-group: n = ng*8 .. ng*8+7
  const float4* w1r = (const float4*)W1;               // row k = 32 float4s
  const float4* es4 = (const float4*)es + ng * 8 * 32;  // rows ng*8.., 32 f4/row

  float acc[4][8];
#pragma unroll
  for (int i = 0; i < 4; ++i)
#pragma unroll
    for (int j = 0; j < 8; ++j) acc[i][j] = 0.f;

  for (int h4 = 0; h4 < 32; ++h4) {
    float4 wp[4];
#pragma unroll
    for (int i = 0; i < 4; ++i) wp[i] = w1r[(size_t)(kq * 4 + i) * 32 + h4];
    float4 e[8];
#pragma unroll
    for (int j = 0; j < 8; ++j) e[j] = es4[j * 32 + h4];
#pragma unroll
    for (int i = 0; i < 4; ++i)
#pragma unroll
      for (int j = 0; j < 8; ++j)
        acc[i][j] += wp[i].x * e[j].x + wp[i].y * e[j].y +
                     wp[i].z * e[j].z + wp[i].w * e[j].w;
  }

#pragma unroll
  for (int i = 0; i < 4; ++i) {
    float* dst = encT2 + (size_t)b * (H * N) + (size_t)(kq * 4 + i) * N + n0 + ng * 8;
    ((float4*)dst)[0] = make_float4(acc[i][0], acc[i][1], acc[i][2], acc[i][3]);
    ((float4*)dst)[1] = make_float4(acc[i][4], acc[i][5], acc[i][6], acc[i][7]);
  }
}

#define REP16(M) M(0) M(1) M(2) M(3) M(4) M(5) M(6) M(7) \
                 M(8) M(9) M(10) M(11) M(12) M(13) M(14) M(15)

// ---- main fused decoder: 1 batch/block, 512 threads (8 waves) -------------
// R10 VERBATIM. Dynamic LDS (128 KB): e_lds[64][512] = encT2[b][64..127][:];
// k 0..63 in 16 named float4 regs. 6 barriers/step, replicated S5 finale.
__global__ __launch_bounds__(512)
__attribute__((amdgpu_waves_per_eu(2, 2))) void k_decode(
    const float* __restrict__ enc, const float* __restrict__ encT2,
    const float* __restrict__ WihT, const float* __restrict__ WhhT,
    const float* __restrict__ W2T,
    const float* __restrict__ bih, const float* __restrict__ bhh,
    const float* __restrict__ v,
    KeyArgs keys, float* __restrict__ out) {
  __shared__ __align__(16) float xs[H];     // dec_input
  __shared__ __align__(16) float hs[H];     // hx
  __shared__ __align__(16) float cs[H];     // cx
  __shared__ __align__(16) float dt[H];     // dec_trans = hx @ W2^T
  __shared__ __align__(16) float vv[H];
  __shared__ __align__(16) float bsum[G4];  // b_ih + b_hh
  __shared__ float pg[G4];                  // gate pre-activations (sans bias)
  __shared__ float pdt[4][H];               // dt partials (and init-mean)
  __shared__ float sc[N];                   // masked scores
  __shared__ float wr_z[8], wr_m[8], wr_s[8];
  __shared__ int wr_i[8];

  extern __shared__ __align__(16) float e_lds[];  // 64*512 floats = 128 KB

  const int tid = threadIdx.x;   // owns node n = tid and gate j = tid
  const int b = blockIdx.x;
  const int lane = tid & 63;
  const int wave = tid >> 6;     // 0..7

  // ---- register-stage encT2[b][0..63][tid]: 16 named float4 (no alloca) ---
  const float* ep = encT2 + (size_t)b * (H * N) + tid;
#define ERLD(i) float4 er##i = make_float4(ep[(size_t)(4*i+0) * N], \
                                           ep[(size_t)(4*i+1) * N], \
                                           ep[(size_t)(4*i+2) * N], \
                                           ep[(size_t)(4*i+3) * N]);
  REP16(ERLD)
#undef ERLD

  // ---- LDS-stage encT2[b][64..127][:] (128 KB), coalesced float4 ----------
  {
    const float4* src4 = (const float4*)(encT2 + (size_t)b * (H * N) + (size_t)64 * N);
    float4* dst4 = (float4*)e_lds;
#pragma unroll
    for (int i = 0; i < 16; ++i) dst4[tid + i * 512] = src4[tid + i * 512];
  }

  // ---- init: dec_input = mean_n enc[b,n,:]; h = c = 0 ----
  {
    int h = tid & 127, part = tid >> 7;
    float s = 0.f;
    const float* p = enc + ((size_t)b * N + part * 128) * H + h;
#pragma unroll 8
    for (int n = 0; n < 128; ++n) s += p[(size_t)n * H];  // coalesced across h
    pdt[part][h] = s;
    bsum[tid] = bih[tid] + bhh[tid];
  }
  if (tid < 128) { hs[tid] = 0.f; cs[tid] = 0.f; vv[tid] = v[tid]; }
  __syncthreads();
  if (tid < 128)
    xs[tid] = (pdt[0][tid] + pdt[1][tid] + pdt[2][tid] + pdt[3][tid]) * (1.0f / N);
  bool masked = false;     // thread tid owns node tid
  int sidx_r = 0;          // previous step's sampled idx (uniform across thr)
  float smax_r = 0.f;      // previous step's score max
  __syncthreads();

  for (int t = 0; t < T; ++t) {
    // === S1: gates (scalar wi/wh loads -- do not touch). Thread 0 also
    // emits the previous step's outputs under the GEMV. ====================
    {
      if (tid == 0 && t > 0) {
        float sum = wr_s[0] + wr_s[1] + wr_s[2] + wr_s[3]
                  + wr_s[4] + wr_s[5] + wr_s[6] + wr_s[7];
        float p = expf(sc[sidx_r] - smax_r) / sum;
        out[(size_t)b * T + (t - 1)] = (float)sidx_r;
        out[(size_t)B * T + (size_t)b * T + (t - 1)] = logf(p + 1e-9f);
      }
      const float* wi = WihT + tid;
      const float* wh = WhhT + tid;
      float a0x = 0.f, a0h = 0.f, a1x = 0.f, a1h = 0.f;
#pragma unroll 8
      for (int h = 0; h < 64; h += 4) {
        const float4 xv = *(const float4*)&xs[h];
        a0x += wi[(size_t)(h + 0) * G4] * xv.x;
        a0x += wi[(size_t)(h + 1) * G4] * xv.y;
        a0x += wi[(size_t)(h + 2) * G4] * xv.z;
        a0x += wi[(size_t)(h + 3) * G4] * xv.w;
        const float4 hv = *(const float4*)&hs[h];
        a0h += wh[(size_t)(h + 0) * G4] * hv.x;
        a0h += wh[(size_t)(h + 1) * G4] * hv.y;
        a0h += wh[(size_t)(h + 2) * G4] * hv.z;
        a0h += wh[(size_t)(h + 3) * G4] * hv.w;
      }
#pragma unroll 8
      for (int h = 64; h < 128; h += 4) {
        const float4 xv = *(const float4*)&xs[h];
        a1x += wi[(size_t)(h + 0) * G4] * xv.x;
        a1x += wi[(size_t)(h + 1) * G4] * xv.y;
        a1x += wi[(size_t)(h + 2) * G4] * xv.z;
        a1x += wi[(size_t)(h + 3) * G4] * xv.w;
        const float4 hv = *(const float4*)&hs[h];
        a1h += wh[(size_t)(h + 0) * G4] * hv.x;
        a1h += wh[(size_t)(h + 1) * G4] * hv.y;
        a1h += wh[(size_t)(h + 2) * G4] * hv.z;
        a1h += wh[(size_t)(h + 3) * G4] * hv.w;
      }
      pg[tid] = (a0x + a0h) + (a1x + a1h);
    }
    __syncthreads();
    // === S2: cell update (torch gate order i,f,g,o) =======================
    if (tid < 128) {
      float gi = pg[tid] + bsum[tid];
      float gf = pg[H + tid] + bsum[H + tid];
      float gg = pg[2 * H + tid] + bsum[2 * H + tid];
      float go = pg[3 * H + tid] + bsum[3 * H + tid];
      gi = 1.0f / (1.0f + expf(-gi));
      gf = 1.0f / (1.0f + expf(-gf));
      gg = tanhf(gg);
      go = 1.0f / (1.0f + expf(-go));
      float c = gf * cs[tid] + gi * gg;
      cs[tid] = c;
      hs[tid] = go * tanhf(c);
    }
    __syncthreads();
    // === S3: dt partials (scalar w2 loads -- do not touch) ================
    {
      int k = tid & 127, part = tid >> 7;
      const float* w2 = W2T + (size_t)(part * 32) * H + k;
      const int hbp = part * 32;
      float a = 0.f;
#pragma unroll 8
      for (int h = 0; h < 32; h += 4) {
        const float4 hv = *(const float4*)&hs[hbp + h];
        a += w2[(size_t)(h + 0) * H] * hv.x;
        a += w2[(size_t)(h + 1) * H] * hv.y;
        a += w2[(size_t)(h + 2) * H] * hv.z;
        a += w2[(size_t)(h + 3) * H] * hv.w;
      }
      pdt[part][k] = a;
    }
    __syncthreads();
    if (tid < 128) dt[tid] = pdt[0][tid] + pdt[1][tid] + pdt[2][tid] + pdt[3][tid];
    __syncthreads();
    // === S4: scores + gumbel + per-wave argmax ============================
    float s;
    {
      float a0 = 0.f, a1 = 0.f;
#define P4A(i) { const float4 dv = *(const float4*)&dt[4 * i];              \
                 const float4 vw = *(const float4*)&vv[4 * i];              \
                 a0 += vw.x * fast_tanh(er##i.x + dv.x);                    \
                 a1 += vw.y * fast_tanh(er##i.y + dv.y);                    \
                 a0 += vw.z * fast_tanh(er##i.z + dv.z);                    \
                 a1 += vw.w * fast_tanh(er##i.w + dv.w); }
      REP16(P4A)
#undef P4A
      float b0 = 0.f, b1 = 0.f;
#pragma unroll
      for (int k4 = 0; k4 < 64; k4 += 4) {
        const float e0 = e_lds[(k4 + 0) * N + tid];
        const float e1 = e_lds[(k4 + 1) * N + tid];
        const float e2 = e_lds[(k4 + 2) * N + tid];
        const float e3 = e_lds[(k4 + 3) * N + tid];
        const float4 dv = *(const float4*)&dt[64 + k4];
        const float4 vw = *(const float4*)&vv[64 + k4];
        b0 += vw.x * fast_tanh(e0 + dv.x);
        b1 += vw.y * fast_tanh(e1 + dv.y);
        b0 += vw.z * fast_tanh(e2 + dv.z);
        b1 += vw.w * fast_tanh(e3 + dv.w);
      }
      const float s_score = (a0 + a1) + (b0 + b1);
      s = masked ? -INFINITY : s_score;
      sc[tid] = s;
      uint32_t bits = gumbel_bits(keys.k[2 * t], keys.k[2 * t + 1], b * N + tid);
      // XLA uniform(minval=tiny, maxval=1): bits->[1,2)->-1, +tiny, max
      float f = __uint_as_float((bits >> 9) | 0x3f800000u) - 1.0f;
      float u = fmaxf(TINYF, f + TINYF);
      float g = -logf(-logf(u));  // accurate logf (hw log2 too sloppy near u~1)
      float z = s + g;
      int zi = tid;
      float m = s;
#pragma unroll
      for (int d = 32; d >= 1; d >>= 1) {
        float oz = __shfl_xor(z, d);
        int oi = __shfl_xor(zi, d);
        float om = __shfl_xor(m, d);
        if (oz > z || (oz == z && oi < zi)) { z = oz; zi = oi; }  // first-idx ties
        m = fmaxf(m, om);
      }
      if (lane == 0) { wr_z[wave] = z; wr_i[wave] = zi; wr_m[wave] = m; }
    }
    __syncthreads();
    // === S5: replicated finale + softmax partials + mask + next dec_input ==
    {
      float bz = wr_z[0]; int bi = wr_i[0]; float bm = wr_m[0];
#pragma unroll
      for (int w = 1; w < 8; ++w) {
        if (wr_z[w] > bz || (wr_z[w] == bz && wr_i[w] < bi)) { bz = wr_z[w]; bi = wr_i[w]; }
        bm = fmaxf(bm, wr_m[w]);
      }
      sidx_r = bi; smax_r = bm;
      float xnew = 0.f;
      if (tid < 128) xnew = enc[((size_t)b * N + bi) * H + tid];  // issue early
      float e = expf(s - bm);  // masked: exp(-inf) = 0
#pragma unroll
      for (int d = 32; d >= 1; d >>= 1) e += __shfl_xor(e, d);
      if (lane == 0) wr_s[wave] = e;
      if (tid == bi) masked = true;
      if (tid < 128) xs[tid] = xnew;
    }
    __syncthreads();
  }
  // epilogue: outputs for the final step
  if (tid == 0) {
    float sum = wr_s[0] + wr_s[1] + wr_s[2] + wr_s[3]
              + wr_s[4] + wr_s[5] + wr_s[6] + wr_s[7];
    float p = expf(sc[sidx_r] - smax_r) / sum;
    out[(size_t)b * T + (T - 1)] = (float)sidx_r;
    out[(size_t)B * T + (size_t)b * T + (T - 1)] = logf(p + 1e-9f);
  }
}

// ---------------------------------------------------------------------------
extern "C" void kernel_launch(void* const* d_in, const int* in_sizes, int n_in,
                              void* d_out, int out_size, void* d_ws, size_t ws_size,
                              hipStream_t stream) {
  (void)in_sizes; (void)n_in; (void)out_size; (void)ws_size;
  const float* enc = (const float*)d_in[0];
  const float* Wih = (const float*)d_in[1];
  const float* Whh = (const float*)d_in[2];
  const float* bih = (const float*)d_in[3];
  const float* bhh = (const float*)d_in[4];
  const float* W1  = (const float*)d_in[5];
  const float* W2  = (const float*)d_in[6];
  const float* v   = (const float*)d_in[7];
  float* out = (float*)d_out;
  float* ws = (float*)d_ws;

  // ws layout (floats): WihT 65536 | WhhT 65536 | W2T 16384 | (gap) | encT2
  float* WihT  = ws;
  float* WhhT  = ws + 65536;
  float* W2T   = ws + 131072;
  float* encT2 = ws + 163840;   // [b][k][n], ~33.5 MB

  KeyArgs keys = make_subkeys();  // pure host arithmetic: capture-safe

  // allow 128KB dynamic LDS for k_decode (host-side attr; capture-safe)
  static bool lds_attr_set = false;
  if (!lds_attr_set) {
    (void)hipFuncSetAttribute(reinterpret_cast<const void*>(k_decode),
                              hipFuncAttributeMaxDynamicSharedMemorySize, 131072);
    lds_attr_set = true;
  }

  // one setup launch: blocks 0..1023 enc_trans, 1024..1599 transposes
  k_setup<<<1600, 256, 0, stream>>>(enc, W1, Wih, Whh, W2,
                                    encT2, WihT, WhhT, W2T);
  k_decode<<<B, 512, 131072, stream>>>(enc, encT2, WihT, WhhT, W2T,
                                       bih, bhh, v, keys, out);
}

// Round 13
// 573.047 us; speedup vs baseline: 1.0475x; 1.0475x over previous
//
#include <hip/hip_runtime.h>
#include <cstdint>
#include <cstddef>

// ---------------------------------------------------------------------------
// Pointer-network decoder: B=128 batches decode T=32 steps over N=512 nodes.
// Round 15 = R11 RESTORED byte-for-byte (session best, 574.5us):
//  - k_transpose: R4 scalar layouts for WihT/WhhT/W2T (R9 proved packing
//    k_decode's streams breaks L2 residency) + W1P float4 pack for enc_trans.
//  - k_enc_trans: retiled 1024x256, thread = 4k x 8n (R11: setup ~105->80us).
//  - k_decode: R10 verbatim (6 barriers/step, replicated S5 finale, er regs +
//    128KB dyn LDS, wg=512 + waves_per_eu(2,2) = the spill-free envelope).
// R12's setup merge regressed (~25us): direct W1 reads lost wave coalescing
// (lane stride 128 floats vs contiguous W1P) and the 32KB static LDS was
// charged to the 576 transpose blocks. Reverted; launch-interval saving
// (~5us) doesn't cover it.
// All accumulation chains bit-identical -> absmax 0.0 (verified R11).
// ---------------------------------------------------------------------------

constexpr int B = 128, N = 512, H = 128, T = 32;
constexpr int G4 = 4 * H;  // 512
constexpr float TINYF = 1.17549435e-38f;  // np.finfo(float32).tiny

// ---- JAX threefry2x32 block cipher (20 rounds) ----------------------------
__host__ __device__ inline uint32_t rotl32(uint32_t v, int d) {
  return (v << d) | (v >> (32 - d));
}

__host__ __device__ inline void tf2x32(uint32_t k0, uint32_t k1,
                                       uint32_t x0, uint32_t x1,
                                       uint32_t& o0, uint32_t& o1) {
  uint32_t ks2 = k0 ^ k1 ^ 0x1BD11BDAu;
  x0 += k0; x1 += k1;
#define TF_R(r) x0 += x1; x1 = rotl32(x1, (r)); x1 ^= x0;
  TF_R(13) TF_R(15) TF_R(26) TF_R(6)
  x0 += k1; x1 += ks2 + 1u;
  TF_R(17) TF_R(29) TF_R(16) TF_R(24)
  x0 += ks2; x1 += k0 + 2u;
  TF_R(13) TF_R(15) TF_R(26) TF_R(6)
  x0 += k0; x1 += k1 + 3u;
  TF_R(17) TF_R(29) TF_R(16) TF_R(24)
  x0 += k1; x1 += ks2 + 4u;
  TF_R(13) TF_R(15) TF_R(26) TF_R(6)
  x0 += ks2; x1 += k0 + 5u;
#undef TF_R
  o0 = x0; o1 = x1;
}

struct KeyArgs { uint32_t k[2 * T]; };  // per-step subkeys, 256 B by value

// Host-side key chain (partitionable split): key0 = (0,42);
// new_key = E_key(0,0), sub = E_key(0,1).
static KeyArgs make_subkeys() {
  KeyArgs ka;
  uint32_t k0 = 0u, k1 = 42u;
  for (int t = 0; t < T; ++t) {
    uint32_t n0, n1, s0, s1;
    tf2x32(k0, k1, 0u, 0u, n0, n1);
    tf2x32(k0, k1, 0u, 1u, s0, s1);
    ka.k[2 * t] = s0; ka.k[2 * t + 1] = s1;
    k0 = n0; k1 = n1;
  }
  return ka;
}

// 32-bit draw i (of 65536) for this step's subkey: w0^w1 of E_sub(0, i)
__device__ inline uint32_t gumbel_bits(uint32_t sk0, uint32_t sk1, int i) {
  uint32_t o0, o1;
  tf2x32(sk0, sk1, 0u, (uint32_t)i, o0, o1);
  return o0 ^ o1;
}

// fast tanh for the score hot loop; abs err ~2e-7 (clamp avoids inf/inf NaN)
__device__ inline float fast_tanh(float x) {
  float cx = fminf(9.0f, fmaxf(-9.0f, x));
  float t = __expf(2.0f * cx);
  return (t - 1.0f) * __builtin_amdgcn_rcpf(t + 1.0f);
}

// ---- setup kernel 1: transpose weights for coalesced access ---------------
// WihT/WhhT/W2T: R4/R10 layouts (scalar-load streams in k_decode -- R9
// proved packing THOSE breaks L2 residency; do not touch).
// 4th slot holds W1P: float4-packed W1P[(h4*128 + k)*4 + c] = W1[k][4*h4+c]
// (only consumed by k_enc_trans).
__global__ void k_transpose(const float* __restrict__ Wih, const float* __restrict__ Whh,
                            const float* __restrict__ W2, const float* __restrict__ W1,
                            float* __restrict__ WihT, float* __restrict__ WhhT,
                            float* __restrict__ W2T, float* __restrict__ W1P) {
  int i = blockIdx.x * blockDim.x + threadIdx.x;
  if (i < H * G4) {
    int h = i >> 9, j = i & (G4 - 1);
    WihT[i] = Wih[j * H + h];
  } else if (i < 2 * H * G4) {
    int q = i - H * G4; int h = q >> 9, j = q & (G4 - 1);
    WhhT[q] = Whh[j * H + h];
  } else if (i < 2 * H * G4 + H * H) {
    int q = i - 2 * H * G4; int h = q >> 7, k = q & (H - 1);
    W2T[q] = W2[k * H + h];
  } else if (i < 2 * H * G4 + 2 * H * H) {
    int q = i - 2 * H * G4 - H * H;
    int c = q & 3, k = (q >> 2) & 127, h4 = q >> 9;
    W1P[q] = W1[k * H + h4 * 4 + c];
  }
}

// ---- setup kernel 2 (retiled): encT2[b,k,n] = sum_h enc[b,n,h]*W1[k,h] ----
// 1024 blocks (128 b x 8 chunks of 64 n-rows) x 256 threads.
// Thread = 4k x 8n tile (kq = tid&31 -> k = kq*4+i; ng = tid>>5 -> n =
// ng*8+j). Per h4-iter: 4x b128 W1P global (L2-hot, coalesced) + 8x b128
// enc LDS (2-address broadcast per wave -> conflict-free).
// Per-output h-chain: ascending h4, acc += w0*ex + w1*ey + w2*ez + w3*ew
// with w0..w3 = W1[k][h..h+3] -- the EXACT expression/order of the original
// kernel -> encT2 bit-identical.
__global__ __launch_bounds__(256) void k_enc_trans(const float* __restrict__ enc,
                                                   const float* __restrict__ W1P,
                                                   float* __restrict__ encT2) {
  __shared__ __align__(16) float es[64 * 128];  // 32 KB
  const int blk = blockIdx.x;
  const int b = blk >> 3;              // 8 blocks per batch
  const int n0 = (blk & 7) << 6;       // 64 rows per block
  const int tid = threadIdx.x;

  // stage enc[b][n0..n0+63][:], coalesced float4
  {
    const float4* src4 = (const float4*)(enc + ((size_t)b * N + n0) * H);
    float4* dst4 = (float4*)es;
#pragma unroll
    for (int i = 0; i < 8; ++i) dst4[tid + i * 256] = src4[tid + i * 256];
  }
  __syncthreads();

  const int kq = tid & 31;             // k-quad: k = kq*4 .. kq*4+3
  const int ng = tid >> 5;             // n-group: n = ng*8 .. ng*8+7
  const float4* w4 = (const float4*)W1P + kq * 4;     // + h4*128 per iter
  const float4* es4 = (const float4*)es + ng * 8 * 32;  // rows ng*8.., 32 f4/row

  float acc[4][8];
#pragma unroll
  for (int i = 0; i < 4; ++i)
#pragma unroll
    for (int j = 0; j < 8; ++j) acc[i][j] = 0.f;

  for (int h4 = 0; h4 < 32; ++h4) {
    float4 wp[4];
#pragma unroll
    for (int i = 0; i < 4; ++i) wp[i] = w4[h4 * 128 + i];
    float4 e[8];
#pragma unroll
    for (int j = 0; j < 8; ++j) e[j] = es4[j * 32 + h4];
#pragma unroll
    for (int i = 0; i < 4; ++i)
#pragma unroll
      for (int j = 0; j < 8; ++j)
        acc[i][j] += wp[i].x * e[j].x + wp[i].y * e[j].y +
                     wp[i].z * e[j].z + wp[i].w * e[j].w;
  }

#pragma unroll
  for (int i = 0; i < 4; ++i) {
    float* dst = encT2 + (size_t)b * (H * N) + (size_t)(kq * 4 + i) * N + n0 + ng * 8;
    ((float4*)dst)[0] = make_float4(acc[i][0], acc[i][1], acc[i][2], acc[i][3]);
    ((float4*)dst)[1] = make_float4(acc[i][4], acc[i][5], acc[i][6], acc[i][7]);
  }
}

#define REP16(M) M(0) M(1) M(2) M(3) M(4) M(5) M(6) M(7) \
                 M(8) M(9) M(10) M(11) M(12) M(13) M(14) M(15)

// ---- main fused decoder: 1 batch/block, 512 threads (8 waves) -------------
// R10 VERBATIM. Dynamic LDS (128 KB): e_lds[64][512] = encT2[b][64..127][:];
// k 0..63 in 16 named float4 regs. 6 barriers/step, replicated S5 finale.
__global__ __launch_bounds__(512)
__attribute__((amdgpu_waves_per_eu(2, 2))) void k_decode(
    const float* __restrict__ enc, const float* __restrict__ encT2,
    const float* __restrict__ WihT, const float* __restrict__ WhhT,
    const float* __restrict__ W2T,
    const float* __restrict__ bih, const float* __restrict__ bhh,
    const float* __restrict__ v,
    KeyArgs keys, float* __restrict__ out) {
  __shared__ __align__(16) float xs[H];     // dec_input
  __shared__ __align__(16) float hs[H];     // hx
  __shared__ __align__(16) float cs[H];     // cx
  __shared__ __align__(16) float dt[H];     // dec_trans = hx @ W2^T
  __shared__ __align__(16) float vv[H];
  __shared__ __align__(16) float bsum[G4];  // b_ih + b_hh
  __shared__ float pg[G4];                  // gate pre-activations (sans bias)
  __shared__ float pdt[4][H];               // dt partials (and init-mean)
  __shared__ float sc[N];                   // masked scores
  __shared__ float wr_z[8], wr_m[8], wr_s[8];
  __shared__ int wr_i[8];

  extern __shared__ __align__(16) float e_lds[];  // 64*512 floats = 128 KB

  const int tid = threadIdx.x;   // owns node n = tid and gate j = tid
  const int b = blockIdx.x;
  const int lane = tid & 63;
  const int wave = tid >> 6;     // 0..7

  // ---- register-stage encT2[b][0..63][tid]: 16 named float4 (no alloca) ---
  const float* ep = encT2 + (size_t)b * (H * N) + tid;
#define ERLD(i) float4 er##i = make_float4(ep[(size_t)(4*i+0) * N], \
                                           ep[(size_t)(4*i+1) * N], \
                                           ep[(size_t)(4*i+2) * N], \
                                           ep[(size_t)(4*i+3) * N]);
  REP16(ERLD)
#undef ERLD

  // ---- LDS-stage encT2[b][64..127][:] (128 KB), coalesced float4 ----------
  {
    const float4* src4 = (const float4*)(encT2 + (size_t)b * (H * N) + (size_t)64 * N);
    float4* dst4 = (float4*)e_lds;
#pragma unroll
    for (int i = 0; i < 16; ++i) dst4[tid + i * 512] = src4[tid + i * 512];
  }

  // ---- init: dec_input = mean_n enc[b,n,:]; h = c = 0 ----
  {
    int h = tid & 127, part = tid >> 7;
    float s = 0.f;
    const float* p = enc + ((size_t)b * N + part * 128) * H + h;
#pragma unroll 8
    for (int n = 0; n < 128; ++n) s += p[(size_t)n * H];  // coalesced across h
    pdt[part][h] = s;
    bsum[tid] = bih[tid] + bhh[tid];
  }
  if (tid < 128) { hs[tid] = 0.f; cs[tid] = 0.f; vv[tid] = v[tid]; }
  __syncthreads();
  if (tid < 128)
    xs[tid] = (pdt[0][tid] + pdt[1][tid] + pdt[2][tid] + pdt[3][tid]) * (1.0f / N);
  bool masked = false;     // thread tid owns node tid
  int sidx_r = 0;          // previous step's sampled idx (uniform across thr)
  float smax_r = 0.f;      // previous step's score max
  __syncthreads();

  for (int t = 0; t < T; ++t) {
    // === S1: gates (scalar wi/wh loads -- do not touch). Thread 0 also
    // emits the previous step's outputs under the GEMV. ====================
    {
      if (tid == 0 && t > 0) {
        float sum = wr_s[0] + wr_s[1] + wr_s[2] + wr_s[3]
                  + wr_s[4] + wr_s[5] + wr_s[6] + wr_s[7];
        float p = expf(sc[sidx_r] - smax_r) / sum;
        out[(size_t)b * T + (t - 1)] = (float)sidx_r;
        out[(size_t)B * T + (size_t)b * T + (t - 1)] = logf(p + 1e-9f);
      }
      const float* wi = WihT + tid;
      const float* wh = WhhT + tid;
      float a0x = 0.f, a0h = 0.f, a1x = 0.f, a1h = 0.f;
#pragma unroll 8
      for (int h = 0; h < 64; h += 4) {
        const float4 xv = *(const float4*)&xs[h];
        a0x += wi[(size_t)(h + 0) * G4] * xv.x;
        a0x += wi[(size_t)(h + 1) * G4] * xv.y;
        a0x += wi[(size_t)(h + 2) * G4] * xv.z;
        a0x += wi[(size_t)(h + 3) * G4] * xv.w;
        const float4 hv = *(const float4*)&hs[h];
        a0h += wh[(size_t)(h + 0) * G4] * hv.x;
        a0h += wh[(size_t)(h + 1) * G4] * hv.y;
        a0h += wh[(size_t)(h + 2) * G4] * hv.z;
        a0h += wh[(size_t)(h + 3) * G4] * hv.w;
      }
#pragma unroll 8
      for (int h = 64; h < 128; h += 4) {
        const float4 xv = *(const float4*)&xs[h];
        a1x += wi[(size_t)(h + 0) * G4] * xv.x;
        a1x += wi[(size_t)(h + 1) * G4] * xv.y;
        a1x += wi[(size_t)(h + 2) * G4] * xv.z;
        a1x += wi[(size_t)(h + 3) * G4] * xv.w;
        const float4 hv = *(const float4*)&hs[h];
        a1h += wh[(size_t)(h + 0) * G4] * hv.x;
        a1h += wh[(size_t)(h + 1) * G4] * hv.y;
        a1h += wh[(size_t)(h + 2) * G4] * hv.z;
        a1h += wh[(size_t)(h + 3) * G4] * hv.w;
      }
      pg[tid] = (a0x + a0h) + (a1x + a1h);
    }
    __syncthreads();
    // === S2: cell update (torch gate order i,f,g,o) =======================
    if (tid < 128) {
      float gi = pg[tid] + bsum[tid];
      float gf = pg[H + tid] + bsum[H + tid];
      float gg = pg[2 * H + tid] + bsum[2 * H + tid];
      float go = pg[3 * H + tid] + bsum[3 * H + tid];
      gi = 1.0f / (1.0f + expf(-gi));
      gf = 1.0f / (1.0f + expf(-gf));
      gg = tanhf(gg);
      go = 1.0f / (1.0f + expf(-go));
      float c = gf * cs[tid] + gi * gg;
      cs[tid] = c;
      hs[tid] = go * tanhf(c);
    }
    __syncthreads();
    // === S3: dt partials (scalar w2 loads -- do not touch) ================
    {
      int k = tid & 127, part = tid >> 7;
      const float* w2 = W2T + (size_t)(part * 32) * H + k;
      const int hbp = part * 32;
      float a = 0.f;
#pragma unroll 8
      for (int h = 0; h < 32; h += 4) {
        const float4 hv = *(const float4*)&hs[hbp + h];
        a += w2[(size_t)(h + 0) * H] * hv.x;
        a += w2[(size_t)(h + 1) * H] * hv.y;
        a += w2[(size_t)(h + 2) * H] * hv.z;
        a += w2[(size_t)(h + 3) * H] * hv.w;
      }
      pdt[part][k] = a;
    }
    __syncthreads();
    if (tid < 128) dt[tid] = pdt[0][tid] + pdt[1][tid] + pdt[2][tid] + pdt[3][tid];
    __syncthreads();
    // === S4: scores + gumbel + per-wave argmax ============================
    float s;
    {
      float a0 = 0.f, a1 = 0.f;
#define P4A(i) { const float4 dv = *(const float4*)&dt[4 * i];              \
                 const float4 vw = *(const float4*)&vv[4 * i];              \
                 a0 += vw.x * fast_tanh(er##i.x + dv.x);                    \
                 a1 += vw.y * fast_tanh(er##i.y + dv.y);                    \
                 a0 += vw.z * fast_tanh(er##i.z + dv.z);                    \
                 a1 += vw.w * fast_tanh(er##i.w + dv.w); }
      REP16(P4A)
#undef P4A
      float b0 = 0.f, b1 = 0.f;
#pragma unroll
      for (int k4 = 0; k4 < 64; k4 += 4) {
        const float e0 = e_lds[(k4 + 0) * N + tid];
        const float e1 = e_lds[(k4 + 1) * N + tid];
        const float e2 = e_lds[(k4 + 2) * N + tid];
        const float e3 = e_lds[(k4 + 3) * N + tid];
        const float4 dv = *(const float4*)&dt[64 + k4];
        const float4 vw = *(const float4*)&vv[64 + k4];
        b0 += vw.x * fast_tanh(e0 + dv.x);
        b1 += vw.y * fast_tanh(e1 + dv.y);
        b0 += vw.z * fast_tanh(e2 + dv.z);
        b1 += vw.w * fast_tanh(e3 + dv.w);
      }
      const float s_score = (a0 + a1) + (b0 + b1);
      s = masked ? -INFINITY : s_score;
      sc[tid] = s;
      uint32_t bits = gumbel_bits(keys.k[2 * t], keys.k[2 * t + 1], b * N + tid);
      // XLA uniform(minval=tiny, maxval=1): bits->[1,2)->-1, +tiny, max
      float f = __uint_as_float((bits >> 9) | 0x3f800000u) - 1.0f;
      float u = fmaxf(TINYF, f + TINYF);
      float g = -logf(-logf(u));  // accurate logf (hw log2 too sloppy near u~1)
      float z = s + g;
      int zi = tid;
      float m = s;
#pragma unroll
      for (int d = 32; d >= 1; d >>= 1) {
        float oz = __shfl_xor(z, d);
        int oi = __shfl_xor(zi, d);
        float om = __shfl_xor(m, d);
        if (oz > z || (oz == z && oi < zi)) { z = oz; zi = oi; }  // first-idx ties
        m = fmaxf(m, om);
      }
      if (lane == 0) { wr_z[wave] = z; wr_i[wave] = zi; wr_m[wave] = m; }
    }
    __syncthreads();
    // === S5: replicated finale + softmax partials + mask + next dec_input ==
    {
      float bz = wr_z[0]; int bi = wr_i[0]; float bm = wr_m[0];
#pragma unroll
      for (int w = 1; w < 8; ++w) {
        if (wr_z[w] > bz || (wr_z[w] == bz && wr_i[w] < bi)) { bz = wr_z[w]; bi = wr_i[w]; }
        bm = fmaxf(bm, wr_m[w]);
      }
      sidx_r = bi; smax_r = bm;
      float xnew = 0.f;
      if (tid < 128) xnew = enc[((size_t)b * N + bi) * H + tid];  // issue early
      float e = expf(s - bm);  // masked: exp(-inf) = 0
#pragma unroll
      for (int d = 32; d >= 1; d >>= 1) e += __shfl_xor(e, d);
      if (lane == 0) wr_s[wave] = e;
      if (tid == bi) masked = true;
      if (tid < 128) xs[tid] = xnew;
    }
    __syncthreads();
  }
  // epilogue: outputs for the final step
  if (tid == 0) {
    float sum = wr_s[0] + wr_s[1] + wr_s[2] + wr_s[3]
              + wr_s[4] + wr_s[5] + wr_s[6] + wr_s[7];
    float p = expf(sc[sidx_r] - smax_r) / sum;
    out[(size_t)b * T + (T - 1)] = (float)sidx_r;
    out[(size_t)B * T + (size_t)b * T + (T - 1)] = logf(p + 1e-9f);
  }
}

// ---------------------------------------------------------------------------
extern "C" void kernel_launch(void* const* d_in, const int* in_sizes, int n_in,
                              void* d_out, int out_size, void* d_ws, size_t ws_size,
                              hipStream_t stream) {
  (void)in_sizes; (void)n_in; (void)out_size; (void)ws_size;
  const float* enc = (const float*)d_in[0];
  const float* Wih = (const float*)d_in[1];
  const float* Whh = (const float*)d_in[2];
  const float* bih = (const float*)d_in[3];
  const float* bhh = (const float*)d_in[4];
  const float* W1  = (const float*)d_in[5];
  const float* W2  = (const float*)d_in[6];
  const float* v   = (const float*)d_in[7];
  float* out = (float*)d_out;
  float* ws = (float*)d_ws;

  // ws layout (floats): WihT 65536 | WhhT 65536 | W2T 16384 | W1P 16384 | encT2 8388608
  float* WihT  = ws;
  float* WhhT  = ws + 65536;
  float* W2T   = ws + 131072;
  float* W1P   = ws + 147456;
  float* encT2 = ws + 163840;   // [b][k][n], ~33.5 MB

  KeyArgs keys = make_subkeys();  // pure host arithmetic: capture-safe

  // allow 128KB dynamic LDS for k_decode (host-side attr; capture-safe)
  static bool lds_attr_set = false;
  if (!lds_attr_set) {
    (void)hipFuncSetAttribute(reinterpret_cast<const void*>(k_decode),
                              hipFuncAttributeMaxDynamicSharedMemorySize, 131072);
    lds_attr_set = true;
  }

  k_transpose<<<640, 256, 0, stream>>>(Wih, Whh, W2, W1, WihT, WhhT, W2T, W1P);
  k_enc_trans<<<B * 8, 256, 0, stream>>>(enc, W1P, encT2);
  k_decode<<<B, 512, 131072, stream>>>(enc, encT2, WihT, WhhT, W2T,
                                       bih, bhh, v, keys, out);
}